// Round 5
// baseline (496.481 us; speedup 1.0000x reference)
//
#include <hip/hip_runtime.h>
#include <hip/hip_cooperative_groups.h>
#include <math.h>

namespace cg = cooperative_groups;

// Problem constants
#define DIM   256
#define NST   256
#define LSEQ  512
#define BAT   2
#define DTSZ  64
#define PCOLS 576
#define NROWS 1024

constexpr float LOG2E = 1.4426950408889634f;

__device__ __forceinline__ float fexp2(float v) {
#if __has_builtin(__builtin_amdgcn_exp2f)
    return __builtin_amdgcn_exp2f(v);
#else
    return exp2f(v);
#endif
}

__device__ __forceinline__ float softplusf(float v) {
    return (v > 20.f) ? v : log1pf(__expf(v));
}

// ===================== Cooperative fused kernel: 512 blocks x 256 =====================
// Capacity: LDS 20KB -> 8 blk/CU; launch_bounds(256,4) -> VGPR<=128 -> 4 blk/CU.
// Max coop grid = 1024 >= 512 launched (2x margin vs round-4's exact-limit failure).
constexpr int CC  = 4;            // chunks over L (coop)
constexpr int LCC = LSEQ / CC;    // 128 steps/chunk
constexpr int GG  = 4;            // d-values per scan block
constexpr int TRE = 4;            // rescan reduce window (part rows = 16)

__global__ __launch_bounds__(256, 4) void fused512(
    const float* __restrict__ x, const float* __restrict__ W_in,
    const float* __restrict__ W_dt, const float* __restrict__ b_dt,
    const float* __restrict__ alpha_log, const float* __restrict__ delta,
    float* __restrict__ PP, float* __restrict__ bet, float* __restrict__ gam,
    float* __restrict__ dtp, float* __restrict__ dtxp,
    float* __restrict__ PS, float* __restrict__ Q, float* __restrict__ out)
{
    cg::grid_group grid = cg::this_grid();
    __shared__ float smem[5120];   // 20 KB, reused per phase
    const int tid = threadIdx.x;
    const int bid = blockIdx.x;

    // ---------- Phase A: split-k proj partials. block = (rowblk of 8) x (ksplit of 4)
    {
        const int kb = bid & 3;
        const int row0 = (bid >> 2) * 8;
        const int k0 = kb * 64;
        float (*xs)[64] = (float(*)[64])smem;   // 8x64 = 2KB
        #pragma unroll
        for (int it = 0; it < 2; ++it) {
            int e = tid + it * 256;
            xs[e >> 6][e & 63] = x[(row0 + (e >> 6)) * DIM + k0 + (e & 63)];
        }
        __syncthreads();
        const int j = tid;
        const bool has2 = (j < 64);
        float a0[8], a1[8], a2[8];
        #pragma unroll
        for (int r = 0; r < 8; ++r) { a0[r] = 0.f; a1[r] = 0.f; a2[r] = 0.f; }
        #pragma unroll 2
        for (int k4 = 0; k4 < 16; ++k4) {
            float w0[4], w1[4], w2[4];
            #pragma unroll
            for (int u = 0; u < 4; ++u) {
                int k = k0 + k4 * 4 + u;
                w0[u] = W_in[k * PCOLS + j];
                w1[u] = W_in[k * PCOLS + 256 + j];
                w2[u] = has2 ? W_in[k * PCOLS + 512 + j] : 0.f;
            }
            #pragma unroll
            for (int r = 0; r < 8; ++r) {
                float4 xv = *(const float4*)&xs[r][k4 * 4];
                const float xa[4] = {xv.x, xv.y, xv.z, xv.w};
                #pragma unroll
                for (int u = 0; u < 4; ++u) {
                    a0[r] = fmaf(xa[u], w0[u], a0[r]);
                    a1[r] = fmaf(xa[u], w1[u], a1[r]);
                    a2[r] = fmaf(xa[u], w2[u], a2[r]);
                }
            }
        }
        #pragma unroll
        for (int r = 0; r < 8; ++r) {
            size_t base = (size_t)(kb * NROWS + row0 + r) * PCOLS;
            PP[base + j]       = a0[r];
            PP[base + 256 + j] = a1[r];
            if (has2) PP[base + 512 + j] = a2[r];
        }
    }
    __threadfence();
    grid.sync();

    // ---------- Phase B: reduce partials + dt GEMM + dtx. block = 2 rows.
    {
        const int r0 = bid * 2;
        const int j = tid;
        const bool has2 = (j < 64);
        float* draw = smem;   // [2][64]
        #pragma unroll
        for (int rr = 0; rr < 2; ++rr) {
            const int r = r0 + rr;
            float s0 = 0.f, s1 = 0.f, s2 = 0.f;
            #pragma unroll
            for (int kb = 0; kb < 4; ++kb) {
                size_t base = (size_t)(kb * NROWS + r) * PCOLS;
                s0 += PP[base + j];
                s1 += PP[base + 256 + j];
                if (has2) s2 += PP[base + 512 + j];
            }
            if (has2) {
                draw[rr * 64 + j] = s0;            // dt_raw
                bet[r * NST + 192 + j] = s1;       // col 256+j
                gam[r * NST + 192 + j] = s2;       // col 512+j
            } else {
                bet[r * NST + (j - 64)] = s0;      // col j
                gam[r * NST + (j - 64)] = s1;      // col 256+j
            }
        }
        __syncthreads();
        float acc[2] = {b_dt[j], b_dt[j]};
        #pragma unroll 8
        for (int k = 0; k < DTSZ; ++k) {
            float w = W_dt[k * DIM + j];
            acc[0] = fmaf(draw[k], w, acc[0]);
            acc[1] = fmaf(draw[64 + k], w, acc[1]);
        }
        #pragma unroll
        for (int rr = 0; rr < 2; ++rr) {
            const int r = r0 + rr;
            float sp = softplusf(acc[rr]);
            dtp[r * DIM + j]  = sp;
            dtxp[r * DIM + j] = sp * x[r * DIM + j];
        }
    }
    __threadfence();
    grid.sync();

    // ---------- Scan mapping: block = (b, dblk(64), c(4))
    const int c    = bid & 3;
    const int dblk = (bid >> 2) & 63;
    const int b    = bid >> 8;
    const int d0   = dblk * GG;
    const int n    = tid;
    const int rbase = b * LSEQ + c * LCC;

    float aln[GG];
    #pragma unroll
    for (int g = 0; g < GG; ++g)
        aln[g] = -__expf(alpha_log[(d0 + g) * NST + n]) * LOG2E;

    // ---------- Phase C: chunk affine summary (p, q) over LCC=128 steps
    {
        float* dts = smem;          // [128][4] = 2KB
        float* dxs = smem + 512;    // [128][4] = 2KB
        #pragma unroll
        for (int it = 0; it < 2; ++it) {
            int e = tid + it * 256;                // 0..511
            int t = e >> 2, g = e & 3;
            dts[e] = dtp [(rbase + t) * DIM + d0 + g];
            dxs[e] = dtxp[(rbase + t) * DIM + d0 + g];
        }
        __syncthreads();

        float p[GG] = {1.f,1.f,1.f,1.f}, q[GG] = {0.f,0.f,0.f,0.f};
        constexpr int W = 8, NW = LCC / W;         // 16 windows
        float be[2][W];
        #pragma unroll
        for (int t = 0; t < W; ++t) be[0][t] = bet[(rbase + t) * NST + n];
        for (int w = 0; w < NW; ++w) {
            const int cur = w & 1, nxt = cur ^ 1;
            if (w + 1 < NW) {
                #pragma unroll
                for (int t = 0; t < W; ++t)
                    be[nxt][t] = bet[(rbase + (w + 1) * W + t) * NST + n];
            }
            #pragma unroll
            for (int t = 0; t < W; ++t) {
                const int l = w * W + t;
                float4 dt4 = *(const float4*)&dts[l * 4];   // LDS broadcast
                float4 dx4 = *(const float4*)&dxs[l * 4];
                const float dta[4] = {dt4.x, dt4.y, dt4.z, dt4.w};
                const float dxa[4] = {dx4.x, dx4.y, dx4.z, dx4.w};
                #pragma unroll
                for (int g = 0; g < GG; ++g) {
                    float a = fexp2(dta[g] * aln[g]);
                    q[g] = fmaf(a, q[g], dxa[g] * be[cur][t]);
                    p[g] *= a;
                }
            }
        }
        #pragma unroll
        for (int g = 0; g < GG; ++g) {
            size_t i = ((size_t)(b * DIM + d0 + g) * CC + c) * NST + n;
            PS[i] = p[g];
            Q[i]  = q[g];
        }
    }
    __threadfence();
    grid.sync();

    // ---------- Phase D: fold entry state from prior chunks (<=3 steps)
    float s[GG] = {0.f, 0.f, 0.f, 0.f};
    for (int cc = 0; cc < c; ++cc) {
        #pragma unroll
        for (int g = 0; g < GG; ++g) {
            size_t i = ((size_t)(b * DIM + d0 + g) * CC + cc) * NST + n;
            s[g] = fmaf(PS[i], s[g], Q[i]);
        }
    }

    // ---------- Phase E: rescan + deferred LDS transpose-reduction
    {
        float (*part)[NST] = (float(*)[NST])smem;   // [16][256] = 16KB
        float* dts = smem + 4096;                   // [128][4]
        float* dxs = smem + 4608;
        #pragma unroll
        for (int it = 0; it < 2; ++it) {
            int e = tid + it * 256;
            int t = e >> 2, g = e & 3;
            dts[e] = dtp [(rbase + t) * DIM + d0 + g];
            dxs[e] = dtxp[(rbase + t) * DIM + d0 + g];
        }
        const float4 dl4 = *(const float4*)(delta + d0);
        __syncthreads();

        constexpr int NW = LCC / TRE;               // 32 windows
        float be[2][TRE], ga[2][TRE];
        #pragma unroll
        for (int t = 0; t < TRE; ++t) {
            be[0][t] = bet[(rbase + t) * NST + n];
            ga[0][t] = gam[(rbase + t) * NST + n];
        }
        for (int w = 0; w < NW; ++w) {
            const int cur = w & 1, nxt = cur ^ 1;
            if (w + 1 < NW) {
                #pragma unroll
                for (int t = 0; t < TRE; ++t) {
                    be[nxt][t] = bet[(rbase + (w + 1) * TRE + t) * NST + n];
                    ga[nxt][t] = gam[(rbase + (w + 1) * TRE + t) * NST + n];
                }
            }
            #pragma unroll
            for (int t = 0; t < TRE; ++t) {
                const int l = w * TRE + t;
                float4 dt4 = *(const float4*)&dts[l * 4];
                float4 dx4 = *(const float4*)&dxs[l * 4];
                const float dta[4] = {dt4.x, dt4.y, dt4.z, dt4.w};
                const float dxa[4] = {dx4.x, dx4.y, dx4.z, dx4.w};
                #pragma unroll
                for (int g = 0; g < GG; ++g) {
                    float a = fexp2(dta[g] * aln[g]);
                    s[g] = fmaf(a, s[g], dxa[g] * be[cur][t]);
                    part[t * GG + g][n] = s[g] * ga[cur][t];   // 2-way alias: free
                }
            }
            __syncthreads();
            {
                // 16 rows x 256 -> 16 sums (round-3 verified scheme)
                const int row = n >> 4, m = n & 15, rw = row & 3;
                float sum = 0.f;
                #pragma unroll
                for (int k = 0; k < 16; ++k) {
                    int col = m * 16 + ((k + m + 5 * rw) & 15);
                    sum += part[row][col];
                }
                sum += __shfl_xor(sum, 1);
                sum += __shfl_xor(sum, 2);
                sum += __shfl_xor(sum, 4);
                sum += __shfl_xor(sum, 8);
                if (m == 0) {
                    const int tt = row >> 2, g = row & 3;
                    const int r = rbase + w * TRE + tt;
                    const int oidx = r * DIM + d0 + g;
                    float dv = (g == 0) ? dl4.x : (g == 1) ? dl4.y
                             : (g == 2) ? dl4.z : dl4.w;
                    out[oidx] = sum + x[oidx] * dv;
                }
            }
            __syncthreads();
        }
    }
}

// ===================== Fallback path (3 kernels, no pass2) =====================
constexpr int CF  = 8;            // chunks (fallback)
constexpr int LCF = LSEQ / CF;    // 64

// round-2 proj verbatim (passed at 136.8us total)
__global__ __launch_bounds__(256) void proj_kernel(
    const float* __restrict__ x, const float* __restrict__ W_in,
    const float* __restrict__ W_dt, const float* __restrict__ b_dt,
    float* __restrict__ bet, float* __restrict__ gam,
    float* __restrict__ dtp, float* __restrict__ dtxp)
{
    __shared__ float xs[2][DIM];
    __shared__ float draw[2][DTSZ];
    const int j = threadIdx.x;
    const int row0 = blockIdx.x * 2;

    #pragma unroll
    for (int r = 0; r < 2; ++r) xs[r][j] = x[(row0 + r) * DIM + j];
    __syncthreads();

    float acc0[2] = {0.f,0.f}, acc1[2] = {0.f,0.f}, acc2[2] = {0.f,0.f};
    const bool has2 = (j < 64);
    #pragma unroll 8
    for (int k = 0; k < DIM; ++k) {
        float w0 = W_in[k * PCOLS + j];
        float w1 = W_in[k * PCOLS + 256 + j];
        float w2 = has2 ? W_in[k * PCOLS + 512 + j] : 0.f;
        #pragma unroll
        for (int r = 0; r < 2; ++r) {
            float xv = xs[r][k];
            acc0[r] = fmaf(xv, w0, acc0[r]);
            acc1[r] = fmaf(xv, w1, acc1[r]);
            acc2[r] = fmaf(xv, w2, acc2[r]);
        }
    }
    #pragma unroll
    for (int r = 0; r < 2; ++r) {
        const int row = row0 + r;
        if (has2) {
            draw[r][j] = acc0[r];
            bet[row * NST + 192 + j] = acc1[r];
            gam[row * NST + 192 + j] = acc2[r];
        } else {
            bet[row * NST + (j - 64)] = acc0[r];
            gam[row * NST + (j - 64)] = acc1[r];
        }
    }
    __syncthreads();
    float bd = b_dt[j];
    float accd[2] = {bd, bd};
    #pragma unroll 8
    for (int k = 0; k < DTSZ; ++k) {
        float w = W_dt[k * DIM + j];
        #pragma unroll
        for (int r = 0; r < 2; ++r) accd[r] = fmaf(draw[r][k], w, accd[r]);
    }
    #pragma unroll
    for (int r = 0; r < 2; ++r) {
        const int row = row0 + r;
        float sp = softplusf(accd[r]);
        dtp[row * DIM + j]  = sp;
        dtxp[row * DIM + j] = sp * xs[r][j];
    }
}

__global__ __launch_bounds__(256, 4) void pass1f(
    const float* __restrict__ alpha_log, const float* __restrict__ bet,
    const float* __restrict__ dtp, const float* __restrict__ dtxp,
    float* __restrict__ PS, float* __restrict__ Q)
{
    __shared__ float dts[LCF * 4], dxs[LCF * 4];   // 256 floats each
    const int n = threadIdx.x;
    const int c = blockIdx.x & 7;
    const int dblk = (blockIdx.x >> 3) & 63;
    const int b = blockIdx.x >> 9;
    const int d0 = dblk * 4;
    const int rbase = b * LSEQ + c * LCF;
    {
        int t = n >> 2, g = n & 3;
        dts[n] = dtp [(rbase + t) * DIM + d0 + g];
        dxs[n] = dtxp[(rbase + t) * DIM + d0 + g];
    }
    float aln[4];
    #pragma unroll
    for (int g = 0; g < 4; ++g)
        aln[g] = -__expf(alpha_log[(d0 + g) * NST + n]) * LOG2E;
    __syncthreads();

    float p[4] = {1.f,1.f,1.f,1.f}, q[4] = {0.f,0.f,0.f,0.f};
    constexpr int W = 8, NW = LCF / W;
    float be[2][W];
    #pragma unroll
    for (int t = 0; t < W; ++t) be[0][t] = bet[(rbase + t) * NST + n];
    #pragma unroll
    for (int w = 0; w < NW; ++w) {
        const int cur = w & 1, nxt = cur ^ 1;
        if (w + 1 < NW) {
            #pragma unroll
            for (int t = 0; t < W; ++t)
                be[nxt][t] = bet[(rbase + (w + 1) * W + t) * NST + n];
        }
        #pragma unroll
        for (int t = 0; t < W; ++t) {
            const int l = w * W + t;
            float4 dt4 = *(const float4*)&dts[l * 4];
            float4 dx4 = *(const float4*)&dxs[l * 4];
            const float dta[4] = {dt4.x, dt4.y, dt4.z, dt4.w};
            const float dxa[4] = {dx4.x, dx4.y, dx4.z, dx4.w};
            #pragma unroll
            for (int g = 0; g < 4; ++g) {
                float a = fexp2(dta[g] * aln[g]);
                q[g] = fmaf(a, q[g], dxa[g] * be[cur][t]);
                p[g] *= a;
            }
        }
    }
    #pragma unroll
    for (int g = 0; g < 4; ++g) {
        size_t i = ((size_t)(b * DIM + d0 + g) * CF + c) * NST + n;
        PS[i] = p[g]; Q[i] = q[g];
    }
}

__global__ __launch_bounds__(256, 4) void pass3f(
    const float* __restrict__ x, const float* __restrict__ alpha_log,
    const float* __restrict__ delta,
    const float* __restrict__ bet, const float* __restrict__ gam,
    const float* __restrict__ dtp, const float* __restrict__ dtxp,
    const float* __restrict__ PS, const float* __restrict__ Q,
    float* __restrict__ out)
{
    __shared__ float part[16][NST];              // 16KB
    __shared__ float dts[LCF * 4], dxs[LCF * 4];
    const int n = threadIdx.x;
    const int c = blockIdx.x & 7;
    const int dblk = (blockIdx.x >> 3) & 63;
    const int b = blockIdx.x >> 9;
    const int d0 = dblk * 4;
    const int rbase = b * LSEQ + c * LCF;
    {
        int t = n >> 2, g = n & 3;
        dts[n] = dtp [(rbase + t) * DIM + d0 + g];
        dxs[n] = dtxp[(rbase + t) * DIM + d0 + g];
    }
    float aln[4], s[4] = {0.f,0.f,0.f,0.f};
    #pragma unroll
    for (int g = 0; g < 4; ++g)
        aln[g] = -__expf(alpha_log[(d0 + g) * NST + n]) * LOG2E;
    for (int cc = 0; cc < c; ++cc) {             // fold entry state (<=7)
        #pragma unroll
        for (int g = 0; g < 4; ++g) {
            size_t i = ((size_t)(b * DIM + d0 + g) * CF + cc) * NST + n;
            s[g] = fmaf(PS[i], s[g], Q[i]);
        }
    }
    const float4 dl4 = *(const float4*)(delta + d0);
    __syncthreads();

    constexpr int TR = 4, NW = LCF / TR;         // 16 windows
    float be[2][TR], ga[2][TR];
    #pragma unroll
    for (int t = 0; t < TR; ++t) {
        be[0][t] = bet[(rbase + t) * NST + n];
        ga[0][t] = gam[(rbase + t) * NST + n];
    }
    #pragma unroll
    for (int w = 0; w < NW; ++w) {
        const int cur = w & 1, nxt = cur ^ 1;
        if (w + 1 < NW) {
            #pragma unroll
            for (int t = 0; t < TR; ++t) {
                be[nxt][t] = bet[(rbase + (w + 1) * TR + t) * NST + n];
                ga[nxt][t] = gam[(rbase + (w + 1) * TR + t) * NST + n];
            }
        }
        #pragma unroll
        for (int t = 0; t < TR; ++t) {
            const int l = w * TR + t;
            float4 dt4 = *(const float4*)&dts[l * 4];
            float4 dx4 = *(const float4*)&dxs[l * 4];
            const float dta[4] = {dt4.x, dt4.y, dt4.z, dt4.w};
            const float dxa[4] = {dx4.x, dx4.y, dx4.z, dx4.w};
            #pragma unroll
            for (int g = 0; g < 4; ++g) {
                float a = fexp2(dta[g] * aln[g]);
                s[g] = fmaf(a, s[g], dxa[g] * be[cur][t]);
                part[t * 4 + g][n] = s[g] * ga[cur][t];
            }
        }
        __syncthreads();
        {
            const int row = n >> 4, m = n & 15, rw = row & 3;
            float sum = 0.f;
            #pragma unroll
            for (int k = 0; k < 16; ++k) {
                int col = m * 16 + ((k + m + 5 * rw) & 15);
                sum += part[row][col];
            }
            sum += __shfl_xor(sum, 1);
            sum += __shfl_xor(sum, 2);
            sum += __shfl_xor(sum, 4);
            sum += __shfl_xor(sum, 8);
            if (m == 0) {
                const int tt = row >> 2, g = row & 3;
                const int r = rbase + w * TR + tt;
                const int oidx = r * DIM + d0 + g;
                float dv = (g == 0) ? dl4.x : (g == 1) ? dl4.y
                         : (g == 2) ? dl4.z : dl4.w;
                out[oidx] = sum + x[oidx] * dv;
            }
        }
        __syncthreads();
    }
}

extern "C" void kernel_launch(void* const* d_in, const int* in_sizes, int n_in,
                              void* d_out, int out_size, void* d_ws, size_t ws_size,
                              hipStream_t stream) {
    const float* x         = (const float*)d_in[0];
    const float* W_in      = (const float*)d_in[1];
    const float* W_dt      = (const float*)d_in[2];
    const float* b_dt      = (const float*)d_in[3];
    const float* alpha_log = (const float*)d_in[4];
    const float* delta     = (const float*)d_in[5];
    float* out = (float*)d_out;

    // Workspace: PP 9.4MB | bet/gam/dtp/dtxp 4MB | PS/Q 8MB (CF=8 sizing covers CC=4)
    float* PP   = (float*)d_ws;
    float* bet  = PP   + (size_t)4 * NROWS * PCOLS;
    float* gam  = bet  + NROWS * NST;
    float* dtp  = gam  + NROWS * NST;
    float* dtxp = dtp  + NROWS * DIM;
    float* PS   = dtxp + NROWS * DIM;
    float* Q    = PS   + (size_t)BAT * DIM * CF * NST;

    void* args[] = {
        (void*)&x, (void*)&W_in, (void*)&W_dt, (void*)&b_dt,
        (void*)&alpha_log, (void*)&delta,
        (void*)&PP, (void*)&bet, (void*)&gam, (void*)&dtp, (void*)&dtxp,
        (void*)&PS, (void*)&Q, (void*)&out
    };
    hipError_t err = hipLaunchCooperativeKernel((const void*)fused512,
                                                dim3(512), dim3(256), args, 0, stream);
    if (err != hipSuccess) {
        // Cooperative launch unavailable -> 3-kernel fallback (same computation).
        proj_kernel<<<NROWS / 2, 256, 0, stream>>>(x, W_in, W_dt, b_dt, bet, gam, dtp, dtxp);
        pass1f<<<BAT * (DIM / 4) * CF, 256, 0, stream>>>(alpha_log, bet, dtp, dtxp, PS, Q);
        pass3f<<<BAT * (DIM / 4) * CF, 256, 0, stream>>>(x, alpha_log, delta, bet, gam,
                                                         dtp, dtxp, PS, Q, out);
    }
}

// Round 6
// 135.724 us; speedup vs baseline: 3.6580x; 3.6580x over previous
//
#include <hip/hip_runtime.h>
#include <math.h>

// Problem constants
#define DIM   256
#define NST   256
#define LSEQ  512
#define BAT   2
#define DTSZ  64
#define PCOLS 576
#define NROWS 1024

constexpr int CF  = 8;            // chunks over L
constexpr int LCF = LSEQ / CF;    // 64 steps/chunk
constexpr float LOG2E = 1.4426950408889634f;

__device__ __forceinline__ float fexp2(float v) {
#if __has_builtin(__builtin_amdgcn_exp2f)
    return __builtin_amdgcn_exp2f(v);
#else
    return exp2f(v);
#endif
}

__device__ __forceinline__ float softplusf(float v) {
    return (v > 20.f) ? v : log1pf(__expf(v));
}

// ---------------- proj: x@W_in (+ dt GEMM + softplus + dt*x). 512 blocks x 256.
// Deep explicit prefetch: 48 loads in flight per k-group of 16.
__global__ __launch_bounds__(256) void proj_kernel(
    const float* __restrict__ x, const float* __restrict__ W_in,
    const float* __restrict__ W_dt, const float* __restrict__ b_dt,
    float* __restrict__ bet, float* __restrict__ gam,
    float* __restrict__ dtp, float* __restrict__ dtxp)
{
    __shared__ float xs[2][DIM];
    __shared__ float draw[2][DTSZ];
    const int j = threadIdx.x;
    const int row0 = blockIdx.x * 2;

    #pragma unroll
    for (int r = 0; r < 2; ++r) xs[r][j] = x[(row0 + r) * DIM + j];
    __syncthreads();

    float acc0[2] = {0.f, 0.f}, acc1[2] = {0.f, 0.f}, acc2[2] = {0.f, 0.f};
    const bool has2 = (j < 64);

    for (int kk = 0; kk < DIM; kk += 16) {
        float w0[16], w1[16], w2[16];
        #pragma unroll
        for (int u = 0; u < 16; ++u) {
            const int k = kk + u;
            w0[u] = W_in[k * PCOLS + j];
            w1[u] = W_in[k * PCOLS + 256 + j];
            w2[u] = has2 ? W_in[k * PCOLS + 512 + j] : 0.f;
        }
        #pragma unroll
        for (int r = 0; r < 2; ++r) {
            #pragma unroll
            for (int q = 0; q < 4; ++q) {
                float4 xv = *(const float4*)&xs[r][kk + q * 4];   // ds_read_b128
                const float xa[4] = {xv.x, xv.y, xv.z, xv.w};
                #pragma unroll
                for (int u = 0; u < 4; ++u) {
                    const int uu = q * 4 + u;
                    acc0[r] = fmaf(xa[u], w0[uu], acc0[r]);
                    acc1[r] = fmaf(xa[u], w1[uu], acc1[r]);
                    acc2[r] = fmaf(xa[u], w2[uu], acc2[r]);
                }
            }
        }
    }

    // proj col split: [0,64)=dt_raw, [64,320)=beta, [320,576)=gamma
    #pragma unroll
    for (int r = 0; r < 2; ++r) {
        const int row = row0 + r;
        if (has2) {
            draw[r][j] = acc0[r];
            bet[row * NST + 192 + j] = acc1[r];     // col 256+j -> beta[192+j]
            gam[row * NST + 192 + j] = acc2[r];     // col 512+j -> gamma[192+j]
        } else {
            bet[row * NST + (j - 64)] = acc0[r];    // col j -> beta[j-64]
            gam[row * NST + (j - 64)] = acc1[r];    // col 256+j -> gamma[j-64]
        }
    }
    __syncthreads();

    float bd = b_dt[j];
    float accd[2] = {bd, bd};
    #pragma unroll 16
    for (int k = 0; k < DTSZ; ++k) {
        float w = W_dt[k * DIM + j];
        #pragma unroll
        for (int r = 0; r < 2; ++r) accd[r] = fmaf(draw[r][k], w, accd[r]);
    }
    #pragma unroll
    for (int r = 0; r < 2; ++r) {
        const int row = row0 + r;
        float sp = softplusf(accd[r]);
        dtp[row * DIM + j]  = sp;
        dtxp[row * DIM + j] = sp * xs[r][j];
    }
}

// ---------------- pass1: per-chunk affine summary (P,Q). 1024 blocks x 256.
__global__ __launch_bounds__(256, 4) void pass1f(
    const float* __restrict__ alpha_log, const float* __restrict__ bet,
    const float* __restrict__ dtp, const float* __restrict__ dtxp,
    float* __restrict__ PS, float* __restrict__ Q)
{
    __shared__ float dts[LCF * 4], dxs[LCF * 4];   // 1 KB each
    const int n = threadIdx.x;
    const int c = blockIdx.x & 7;
    const int dblk = (blockIdx.x >> 3) & 63;
    const int b = blockIdx.x >> 9;
    const int d0 = dblk * 4;
    const int rbase = b * LSEQ + c * LCF;
    {
        int t = n >> 2, g = n & 3;
        dts[n] = dtp [(rbase + t) * DIM + d0 + g];
        dxs[n] = dtxp[(rbase + t) * DIM + d0 + g];
    }
    float aln[4];
    #pragma unroll
    for (int g = 0; g < 4; ++g)
        aln[g] = -__expf(alpha_log[(d0 + g) * NST + n]) * LOG2E;
    __syncthreads();

    float p[4] = {1.f,1.f,1.f,1.f}, q[4] = {0.f,0.f,0.f,0.f};
    constexpr int W = 8, NW = LCF / W;   // 8 windows
    float be[2][W];
    #pragma unroll
    for (int t = 0; t < W; ++t) be[0][t] = bet[(rbase + t) * NST + n];
    #pragma unroll 2
    for (int w = 0; w < NW; ++w) {
        const int cur = w & 1, nxt = cur ^ 1;
        if (w + 1 < NW) {
            #pragma unroll
            for (int t = 0; t < W; ++t)
                be[nxt][t] = bet[(rbase + (w + 1) * W + t) * NST + n];
        }
        #pragma unroll
        for (int t = 0; t < W; ++t) {
            const int l = w * W + t;
            float4 dt4 = *(const float4*)&dts[l * 4];   // LDS broadcast b128
            float4 dx4 = *(const float4*)&dxs[l * 4];
            const float dta[4] = {dt4.x, dt4.y, dt4.z, dt4.w};
            const float dxa[4] = {dx4.x, dx4.y, dx4.z, dx4.w};
            #pragma unroll
            for (int g = 0; g < 4; ++g) {
                float a = fexp2(dta[g] * aln[g]);
                q[g] = fmaf(a, q[g], dxa[g] * be[cur][t]);
                p[g] *= a;
            }
        }
    }
    #pragma unroll
    for (int g = 0; g < 4; ++g) {
        size_t i = ((size_t)(b * DIM + d0 + g) * CF + c) * NST + n;
        PS[i] = p[g]; Q[i] = q[g];
    }
}

// ---------------- pass3: fold entry state from (P,Q), rescan, emit y. 1024 blocks.
__global__ __launch_bounds__(256, 4) void pass3f(
    const float* __restrict__ x, const float* __restrict__ alpha_log,
    const float* __restrict__ delta,
    const float* __restrict__ bet, const float* __restrict__ gam,
    const float* __restrict__ dtp, const float* __restrict__ dtxp,
    const float* __restrict__ PS, const float* __restrict__ Q,
    float* __restrict__ out)
{
    __shared__ float part[16][NST];               // 16 KB
    __shared__ float dts[LCF * 4], dxs[LCF * 4];
    const int n = threadIdx.x;
    const int c = blockIdx.x & 7;
    const int dblk = (blockIdx.x >> 3) & 63;
    const int b = blockIdx.x >> 9;
    const int d0 = dblk * 4;
    const int rbase = b * LSEQ + c * LCF;
    {
        int t = n >> 2, g = n & 3;
        dts[n] = dtp [(rbase + t) * DIM + d0 + g];
        dxs[n] = dtxp[(rbase + t) * DIM + d0 + g];
    }
    float aln[4], s[4] = {0.f,0.f,0.f,0.f};
    #pragma unroll
    for (int g = 0; g < 4; ++g)
        aln[g] = -__expf(alpha_log[(d0 + g) * NST + n]) * LOG2E;
    for (int cc = 0; cc < c; ++cc) {              // entry-state fold (<=7 steps)
        #pragma unroll
        for (int g = 0; g < 4; ++g) {
            size_t i = ((size_t)(b * DIM + d0 + g) * CF + cc) * NST + n;
            s[g] = fmaf(PS[i], s[g], Q[i]);
        }
    }
    const float4 dl4 = *(const float4*)(delta + d0);
    __syncthreads();

    constexpr int TR = 4, NW = LCF / TR;          // 16 windows
    float be[2][TR], ga[2][TR];
    #pragma unroll
    for (int t = 0; t < TR; ++t) {
        be[0][t] = bet[(rbase + t) * NST + n];
        ga[0][t] = gam[(rbase + t) * NST + n];
    }
    #pragma unroll 2
    for (int w = 0; w < NW; ++w) {
        const int cur = w & 1, nxt = cur ^ 1;
        if (w + 1 < NW) {
            #pragma unroll
            for (int t = 0; t < TR; ++t) {
                be[nxt][t] = bet[(rbase + (w + 1) * TR + t) * NST + n];
                ga[nxt][t] = gam[(rbase + (w + 1) * TR + t) * NST + n];
            }
        }
        #pragma unroll
        for (int t = 0; t < TR; ++t) {
            const int l = w * TR + t;
            float4 dt4 = *(const float4*)&dts[l * 4];
            float4 dx4 = *(const float4*)&dxs[l * 4];
            const float dta[4] = {dt4.x, dt4.y, dt4.z, dt4.w};
            const float dxa[4] = {dx4.x, dx4.y, dx4.z, dx4.w};
            #pragma unroll
            for (int g = 0; g < 4; ++g) {
                float a = fexp2(dta[g] * aln[g]);
                s[g] = fmaf(a, s[g], dxa[g] * be[cur][t]);
                part[t * 4 + g][n] = s[g] * ga[cur][t];   // 2-way alias: free
            }
        }
        __syncthreads();
        {
            // 16 rows x 256 -> 16 sums (round-3 measured: 0 bank conflicts)
            const int row = n >> 4, m = n & 15, rw = row & 3;
            float sum = 0.f;
            #pragma unroll
            for (int k = 0; k < 16; ++k) {
                int col = m * 16 + ((k + m + 5 * rw) & 15);
                sum += part[row][col];
            }
            sum += __shfl_xor(sum, 1);
            sum += __shfl_xor(sum, 2);
            sum += __shfl_xor(sum, 4);
            sum += __shfl_xor(sum, 8);
            if (m == 0) {
                const int tt = row >> 2, g = row & 3;
                const int r = rbase + w * TR + tt;
                const int oidx = r * DIM + d0 + g;
                float dv = (g == 0) ? dl4.x : (g == 1) ? dl4.y
                         : (g == 2) ? dl4.z : dl4.w;
                out[oidx] = sum + x[oidx] * dv;
            }
        }
        __syncthreads();
    }
}

extern "C" void kernel_launch(void* const* d_in, const int* in_sizes, int n_in,
                              void* d_out, int out_size, void* d_ws, size_t ws_size,
                              hipStream_t stream) {
    const float* x         = (const float*)d_in[0];
    const float* W_in      = (const float*)d_in[1];
    const float* W_dt      = (const float*)d_in[2];
    const float* b_dt      = (const float*)d_in[3];
    const float* alpha_log = (const float*)d_in[4];
    const float* delta     = (const float*)d_in[5];
    float* out = (float*)d_out;

    // Workspace: bet/gam/dtp/dtxp 4MB + PS/Q 8MB = 12 MB
    float* bet  = (float*)d_ws;
    float* gam  = bet  + NROWS * NST;
    float* dtp  = gam  + NROWS * NST;
    float* dtxp = dtp  + NROWS * DIM;
    float* PS   = dtxp + NROWS * DIM;
    float* Q    = PS   + (size_t)BAT * DIM * CF * NST;

    proj_kernel<<<NROWS / 2, 256, 0, stream>>>(x, W_in, W_dt, b_dt, bet, gam, dtp, dtxp);
    pass1f<<<BAT * (DIM / 4) * CF, 256, 0, stream>>>(alpha_log, bet, dtp, dtxp, PS, Q);
    pass3f<<<BAT * (DIM / 4) * CF, 256, 0, stream>>>(x, alpha_log, delta, bet, gam,
                                                     dtp, dtxp, PS, Q, out);
}

// Round 7
// 133.789 us; speedup vs baseline: 3.7109x; 1.0145x over previous
//
#include <hip/hip_runtime.h>
#include <math.h>

// Problem constants
#define DIM   256
#define NST   256
#define LSEQ  512
#define BAT   2
#define DTSZ  64
#define PCOLS 576
#define NROWS 1024

constexpr int CF  = 8;            // chunks over L
constexpr int LCF = LSEQ / CF;    // 64 steps/chunk
constexpr int G   = 2;            // d-values per scan block (was 4): 2048 blocks -> 8/CU
constexpr float LOG2E = 1.4426950408889634f;

__device__ __forceinline__ float fexp2(float v) {
#if __has_builtin(__builtin_amdgcn_exp2f)
    return __builtin_amdgcn_exp2f(v);
#else
    return exp2f(v);
#endif
}

__device__ __forceinline__ float softplusf(float v) {
    return (v > 20.f) ? v : log1pf(__expf(v));
}

// ---------------- proj: x@W_in (+ dt GEMM + softplus + dt*x). 512 blocks x 256.
// (unchanged from round 6)
__global__ __launch_bounds__(256) void proj_kernel(
    const float* __restrict__ x, const float* __restrict__ W_in,
    const float* __restrict__ W_dt, const float* __restrict__ b_dt,
    float* __restrict__ bet, float* __restrict__ gam,
    float* __restrict__ dtp, float* __restrict__ dtxp)
{
    __shared__ float xs[2][DIM];
    __shared__ float draw[2][DTSZ];
    const int j = threadIdx.x;
    const int row0 = blockIdx.x * 2;

    #pragma unroll
    for (int r = 0; r < 2; ++r) xs[r][j] = x[(row0 + r) * DIM + j];
    __syncthreads();

    float acc0[2] = {0.f, 0.f}, acc1[2] = {0.f, 0.f}, acc2[2] = {0.f, 0.f};
    const bool has2 = (j < 64);

    for (int kk = 0; kk < DIM; kk += 16) {
        float w0[16], w1[16], w2[16];
        #pragma unroll
        for (int u = 0; u < 16; ++u) {
            const int k = kk + u;
            w0[u] = W_in[k * PCOLS + j];
            w1[u] = W_in[k * PCOLS + 256 + j];
            w2[u] = has2 ? W_in[k * PCOLS + 512 + j] : 0.f;
        }
        #pragma unroll
        for (int r = 0; r < 2; ++r) {
            #pragma unroll
            for (int q = 0; q < 4; ++q) {
                float4 xv = *(const float4*)&xs[r][kk + q * 4];
                const float xa[4] = {xv.x, xv.y, xv.z, xv.w};
                #pragma unroll
                for (int u = 0; u < 4; ++u) {
                    const int uu = q * 4 + u;
                    acc0[r] = fmaf(xa[u], w0[uu], acc0[r]);
                    acc1[r] = fmaf(xa[u], w1[uu], acc1[r]);
                    acc2[r] = fmaf(xa[u], w2[uu], acc2[r]);
                }
            }
        }
    }

    #pragma unroll
    for (int r = 0; r < 2; ++r) {
        const int row = row0 + r;
        if (has2) {
            draw[r][j] = acc0[r];
            bet[row * NST + 192 + j] = acc1[r];
            gam[row * NST + 192 + j] = acc2[r];
        } else {
            bet[row * NST + (j - 64)] = acc0[r];
            gam[row * NST + (j - 64)] = acc1[r];
        }
    }
    __syncthreads();

    float bd = b_dt[j];
    float accd[2] = {bd, bd};
    #pragma unroll 16
    for (int k = 0; k < DTSZ; ++k) {
        float w = W_dt[k * DIM + j];
        #pragma unroll
        for (int r = 0; r < 2; ++r) accd[r] = fmaf(draw[r][k], w, accd[r]);
    }
    #pragma unroll
    for (int r = 0; r < 2; ++r) {
        const int row = row0 + r;
        float sp = softplusf(accd[r]);
        dtp[row * DIM + j]  = sp;
        dtxp[row * DIM + j] = sp * xs[r][j];
    }
}

// ---------------- pass1: per-chunk affine summary (P,Q). G=2 -> 2048 blocks x 256.
// launch_bounds(256,8): cap VGPR at 64 -> up to 8 waves/SIMD (100% occupancy).
__global__ __launch_bounds__(256, 8) void pass1f(
    const float* __restrict__ alpha_log, const float* __restrict__ bet,
    const float* __restrict__ dtp, const float* __restrict__ dtxp,
    float* __restrict__ PS, float* __restrict__ Q)
{
    __shared__ float dts[LCF * G], dxs[LCF * G];   // 512 B each
    const int n = threadIdx.x;
    const int c = blockIdx.x & 7;
    const int dblk = (blockIdx.x >> 3) & 127;
    const int b = blockIdx.x >> 10;
    const int d0 = dblk * G;
    const int rbase = b * LSEQ + c * LCF;
    {
        int e = n & 127, t = e >> 1, g = e & 1;
        if (n < 128) dts[e] = dtp [(rbase + t) * DIM + d0 + g];
        else         dxs[e] = dtxp[(rbase + t) * DIM + d0 + g];
    }
    float aln[G];
    #pragma unroll
    for (int g = 0; g < G; ++g)
        aln[g] = -__expf(alpha_log[(d0 + g) * NST + n]) * LOG2E;
    __syncthreads();

    float p[G] = {1.f, 1.f}, q[G] = {0.f, 0.f};
    constexpr int W = 8, NW = LCF / W;   // 8 windows
    float be[2][W];
    #pragma unroll
    for (int t = 0; t < W; ++t) be[0][t] = bet[(rbase + t) * NST + n];
    #pragma unroll 2
    for (int w = 0; w < NW; ++w) {
        const int cur = w & 1, nxt = cur ^ 1;
        if (w + 1 < NW) {
            #pragma unroll
            for (int t = 0; t < W; ++t)
                be[nxt][t] = bet[(rbase + (w + 1) * W + t) * NST + n];
        }
        #pragma unroll
        for (int t = 0; t < W; ++t) {
            const int l = w * W + t;
            float2 dt2 = *(const float2*)&dts[l * G];   // ds_read_b64 broadcast
            float2 dx2 = *(const float2*)&dxs[l * G];
            const float dta[2] = {dt2.x, dt2.y};
            const float dxa[2] = {dx2.x, dx2.y};
            #pragma unroll
            for (int g = 0; g < G; ++g) {
                float a = fexp2(dta[g] * aln[g]);
                q[g] = fmaf(a, q[g], dxa[g] * be[cur][t]);
                p[g] *= a;
            }
        }
    }
    #pragma unroll
    for (int g = 0; g < G; ++g) {
        size_t i = ((size_t)(b * DIM + d0 + g) * CF + c) * NST + n;
        PS[i] = p[g]; Q[i] = q[g];
    }
}

// ---------------- pass3: fold entry state, rescan, emit y. G=2 -> 2048 blocks x 256.
__global__ __launch_bounds__(256, 4) void pass3f(
    const float* __restrict__ x, const float* __restrict__ alpha_log,
    const float* __restrict__ delta,
    const float* __restrict__ bet, const float* __restrict__ gam,
    const float* __restrict__ dtp, const float* __restrict__ dtxp,
    const float* __restrict__ PS, const float* __restrict__ Q,
    float* __restrict__ out)
{
    constexpr int TR = 8;                          // reduce window: part rows = TR*G = 16
    __shared__ float part[TR * G][NST];            // 16 KB
    __shared__ float dts[LCF * G], dxs[LCF * G];
    const int n = threadIdx.x;
    const int c = blockIdx.x & 7;
    const int dblk = (blockIdx.x >> 3) & 127;
    const int b = blockIdx.x >> 10;
    const int d0 = dblk * G;
    const int rbase = b * LSEQ + c * LCF;
    {
        int e = n & 127, t = e >> 1, g = e & 1;
        if (n < 128) dts[e] = dtp [(rbase + t) * DIM + d0 + g];
        else         dxs[e] = dtxp[(rbase + t) * DIM + d0 + g];
    }
    float aln[G], s[G] = {0.f, 0.f};
    #pragma unroll
    for (int g = 0; g < G; ++g)
        aln[g] = -__expf(alpha_log[(d0 + g) * NST + n]) * LOG2E;
    for (int cc = 0; cc < c; ++cc) {               // entry-state fold (<=7 steps)
        #pragma unroll
        for (int g = 0; g < G; ++g) {
            size_t i = ((size_t)(b * DIM + d0 + g) * CF + cc) * NST + n;
            s[g] = fmaf(PS[i], s[g], Q[i]);
        }
    }
    const float2 dl2 = *(const float2*)(delta + d0);
    __syncthreads();

    constexpr int NW = LCF / TR;                   // 8 windows
    float be[2][TR], ga[2][TR];
    #pragma unroll
    for (int t = 0; t < TR; ++t) {
        be[0][t] = bet[(rbase + t) * NST + n];
        ga[0][t] = gam[(rbase + t) * NST + n];
    }
    #pragma unroll 2
    for (int w = 0; w < NW; ++w) {
        const int cur = w & 1, nxt = cur ^ 1;
        if (w + 1 < NW) {
            #pragma unroll
            for (int t = 0; t < TR; ++t) {
                be[nxt][t] = bet[(rbase + (w + 1) * TR + t) * NST + n];
                ga[nxt][t] = gam[(rbase + (w + 1) * TR + t) * NST + n];
            }
        }
        #pragma unroll
        for (int t = 0; t < TR; ++t) {
            const int l = w * TR + t;
            float2 dt2 = *(const float2*)&dts[l * G];
            float2 dx2 = *(const float2*)&dxs[l * G];
            const float dta[2] = {dt2.x, dt2.y};
            const float dxa[2] = {dx2.x, dx2.y};
            #pragma unroll
            for (int g = 0; g < G; ++g) {
                float a = fexp2(dta[g] * aln[g]);
                s[g] = fmaf(a, s[g], dxa[g] * be[cur][t]);
                part[t * G + g][n] = s[g] * ga[cur][t];   // 2-way alias: free
            }
        }
        __syncthreads();
        {
            // 16 rows x 256 -> 16 sums (round-3 measured: 0 bank conflicts)
            const int row = n >> 4, m = n & 15, rw = row & 3;
            float sum = 0.f;
            #pragma unroll
            for (int k = 0; k < 16; ++k) {
                int col = m * 16 + ((k + m + 5 * rw) & 15);
                sum += part[row][col];
            }
            sum += __shfl_xor(sum, 1);
            sum += __shfl_xor(sum, 2);
            sum += __shfl_xor(sum, 4);
            sum += __shfl_xor(sum, 8);
            if (m == 0) {
                const int tt = row >> 1, g = row & 1;   // row = tt*G + g
                const int r = rbase + w * TR + tt;
                const int oidx = r * DIM + d0 + g;
                float dv = (g == 0) ? dl2.x : dl2.y;
                out[oidx] = sum + x[oidx] * dv;
            }
        }
        __syncthreads();
    }
}

extern "C" void kernel_launch(void* const* d_in, const int* in_sizes, int n_in,
                              void* d_out, int out_size, void* d_ws, size_t ws_size,
                              hipStream_t stream) {
    const float* x         = (const float*)d_in[0];
    const float* W_in      = (const float*)d_in[1];
    const float* W_dt      = (const float*)d_in[2];
    const float* b_dt      = (const float*)d_in[3];
    const float* alpha_log = (const float*)d_in[4];
    const float* delta     = (const float*)d_in[5];
    float* out = (float*)d_out;

    // Workspace: bet/gam/dtp/dtxp 4MB + PS/Q 8MB = 12 MB
    float* bet  = (float*)d_ws;
    float* gam  = bet  + NROWS * NST;
    float* dtp  = gam  + NROWS * NST;
    float* dtxp = dtp  + NROWS * DIM;
    float* PS   = dtxp + NROWS * DIM;
    float* Q    = PS   + (size_t)BAT * DIM * CF * NST;

    proj_kernel<<<NROWS / 2, 256, 0, stream>>>(x, W_in, W_dt, b_dt, bet, gam, dtp, dtxp);
    pass1f<<<BAT * (DIM / G) * CF, 256, 0, stream>>>(alpha_log, bet, dtp, dtxp, PS, Q);
    pass3f<<<BAT * (DIM / G) * CF, 256, 0, stream>>>(x, alpha_log, delta, bet, gam,
                                                     dtp, dtxp, PS, Q, out);
}